// Round 6
// baseline (32.091 us; speedup 1.0000x reference)
//
#include <hip/hip_runtime.h>
#include <math.h>

#define LEN       16384
#define NTHREADS  1024
#define SEG       16          // LEN / NTHREADS
#define NWAVES    16
#define RPB       2           // rows per block (register-prefetch pipelined)

// exp(-1/20) and derived constants (double-precision values)
#define DECAY_F 0.951229424500714f      // d = exp(-0.05)
#define D16_F   0.449328964117222f      // d^16 = exp(-0.8)
#define G16_F   7.5886329f              // sum_{i=1..16} d^(2i)

// Full XOR swizzle (word granularity): conflict-free reads (2 lanes/bank),
// 2-way writes (free). XOR touches only bits 0..4 -> stays inside each wave's
// private 1024-word chunk (wave-sync safe). 0 conflicts verified r1/r2/r5.
__device__ __forceinline__ int swz(int a) { return a ^ ((a >> 5) & 31); }

// one scan step: s = d*s + x; A += s^2; Bc += d^(i+1)*s  (ww constant-folds)
#define STEP(xv) { s = __builtin_fmaf(DECAY_F, s, (xv)); ww *= DECAY_F; \
                   A = __builtin_fmaf(s, s, A); Bc = __builtin_fmaf(ww, s, Bc); }

// diff of one float4 pair -> swizzled LDS
#define DSW(base4, A4, B4) { const int _b = (base4) * 4; \
    smem[swz(_b + 0)] = (A4).x - (B4).x; smem[swz(_b + 1)] = (A4).y - (B4).y; \
    smem[swz(_b + 2)] = (A4).z - (B4).z; smem[swz(_b + 3)] = (A4).w - (B4).w; }

__global__ __launch_bounds__(NTHREADS) void vr_main(
    const float* __restrict__ in, const float* __restrict__ tgt,
    float* __restrict__ partial)
{
    __shared__ float smem[LEN];                 // 64 KiB
    __shared__ float wa[NWAVES], wb[NWAVES], red[NWAVES];

    const int tid  = threadIdx.x;
    const int lane = tid & 63;
    const int wid  = tid >> 6;
    // Wave-private chunk: wave w owns words [1024w, 1024w+1024).
    const int cb4 = (wid << 8) + lane;          // float4 index base

    const long long row0 = (long long)blockIdx.x * RPB;
    const float4* __restrict__ in4 = (const float4*)(in  + row0 * LEN);
    const float4* __restrict__ tg4 = (const float4*)(tgt + row0 * LEN);

    // ---- prologue: row 0 loads (8 coalesced float4, kept live in regs) ----
    float4 a0 = in4[cb4];       float4 b0 = tg4[cb4];
    float4 a1 = in4[cb4 +  64]; float4 b1 = tg4[cb4 +  64];
    float4 a2 = in4[cb4 + 128]; float4 b2 = tg4[cb4 + 128];
    float4 a3 = in4[cb4 + 192]; float4 b3 = tg4[cb4 + 192];

    float acc = 0.f;

    #pragma unroll
    for (int r = 0; r < RPB; ++r) {
        // ---- stage current row: diff -> swizzled LDS (own wave chunk) ----
        DSW(cb4,       a0, b0)
        DSW(cb4 +  64, a1, b1)
        DSW(cb4 + 128, a2, b2)
        DSW(cb4 + 192, a3, b3)

        // ---- prefetch next row NOW: HBM latency hides under this row's
        //      scan + stitch (vmcnt, unaffected by the lgkm wait below) ----
        if (r + 1 < RPB) {
            const float4* __restrict__ i4n =
                (const float4*)(in  + (row0 + r + 1) * LEN);
            const float4* __restrict__ t4n =
                (const float4*)(tgt + (row0 + r + 1) * LEN);
            a0 = i4n[cb4];       b0 = t4n[cb4];
            a1 = i4n[cb4 +  64]; b1 = t4n[cb4 +  64];
            a2 = i4n[cb4 + 128]; b2 = t4n[cb4 + 128];
            a3 = i4n[cb4 + 192]; b3 = t4n[cb4 + 192];
        }
        __builtin_amdgcn_sched_barrier(0);      // keep prefetch issued above
        // Wave-local: our ds_writes retired before our ds_reads.
        asm volatile("s_waitcnt lgkmcnt(0)" ::: "memory");
        __builtin_amdgcn_sched_barrier(0);

        // ---- per-thread local scan + moments (segment = tid) ----
        // s_i from zero carry; true y_i = s_i + d^(i+1)*c.
        // sum y^2 = A + 2c*Bc + c^2*G16.
        float s = 0.f, A = 0.f, Bc = 0.f, ww = 1.f;
        const int base = tid * SEG;
        #pragma unroll
        for (int i = 0; i < SEG; ++i) {
            const float x = smem[swz(base + i)];
            STEP(x)
        }

        // ---- affine scan of carries: f(c) = a*c + b, low->high ----
        float aa = D16_F, bb = s;
        #pragma unroll
        for (int j = 1; j < 64; j <<= 1) {
            const float au = __shfl_up(aa, j);
            const float bu = __shfl_up(bb, j);
            if (lane >= j) {
                bb = __builtin_fmaf(aa, bu, bb);
                aa *= au;
            }
        }
        if (lane == 63) { wa[wid] = aa; wb[wid] = bb; }
        __syncthreads();

        // carry entering this wave, then this thread
        float C = 0.f;
        for (int k = 0; k < wid; ++k) C = __builtin_fmaf(wa[k], C, wb[k]);
        float aex = __shfl_up(aa, 1);
        float bex = __shfl_up(bb, 1);
        if (lane == 0) { aex = 1.f; bex = 0.f; }
        const float c = __builtin_fmaf(aex, C, bex);

        acc += A + 2.f * c * Bc + (c * c) * G16_F;

        if (r + 1 < RPB) __syncthreads();       // wa/wb reuse guard
    }

    // ---- block reduce once (deterministic), one partial per block ----
    #pragma unroll
    for (int j = 32; j > 0; j >>= 1) acc += __shfl_down(acc, j);
    if (lane == 0) red[wid] = acc;
    __syncthreads();
    if (tid == 0) {
        float t = 0.f;
        #pragma unroll
        for (int k = 0; k < NWAVES; ++k) t += red[k];
        partial[blockIdx.x] = t;
    }
}

__global__ __launch_bounds__(1024) void vr_final(
    const float* __restrict__ partial, int n, float* __restrict__ out)
{
    __shared__ float red[16];
    const int tid = threadIdx.x;
    float v = 0.f;
    for (int k = tid; k < n; k += 1024) v += partial[k];
    #pragma unroll
    for (int j = 32; j > 0; j >>= 1) v += __shfl_down(v, j);
    const int lane = tid & 63, wid = tid >> 6;
    if (lane == 0) red[wid] = v;
    __syncthreads();
    if (tid == 0) {
        float t = 0.f;
        #pragma unroll
        for (int k = 0; k < 16; ++k) t += red[k];
        out[0] = sqrtf(t * 0.05f);   // sqrt((1/TAU) * sum * DT)
    }
}

extern "C" void kernel_launch(void* const* d_in, const int* in_sizes, int n_in,
                              void* d_out, int out_size, void* d_ws, size_t ws_size,
                              hipStream_t stream) {
    const float* in  = (const float*)d_in[0];
    const float* tgt = (const float*)d_in[1];
    float* out = (float*)d_out;
    float* ws  = (float*)d_ws;              // nblocks floats of scratch
    const int rows    = in_sizes[0] / LEN;  // 1024
    const int nblocks = rows / RPB;         // 512

    vr_main<<<dim3(nblocks), dim3(NTHREADS), 0, stream>>>(in, tgt, ws);
    vr_final<<<dim3(1), dim3(1024), 0, stream>>>(ws, nblocks, out);
}